// Round 6
// baseline (395.948 us; speedup 1.0000x reference)
//
#include <hip/hip_runtime.h>

constexpr int Tq = 2048;
constexpr int Dq = 1024;

typedef __bf16 bf16x8 __attribute__((ext_vector_type(8)));
typedef float f32x4 __attribute__((ext_vector_type(4)));
typedef _Float16 f16;
typedef f16 f16x4 __attribute__((ext_vector_type(4)));
typedef f16 f16x8v __attribute__((ext_vector_type(8)));
typedef unsigned short u16;
typedef u16 u16x4 __attribute__((ext_vector_type(4)));
typedef u16 u16x8 __attribute__((ext_vector_type(8)));

__device__ __forceinline__ u16 f2bf(float f) {
    unsigned int u = __float_as_uint(f);
    u += 0x7fffu + ((u >> 16) & 1u);   // RNE
    return (u16)(u >> 16);
}
__device__ __forceinline__ float bf2f(u16 h) {
    return __uint_as_float(((unsigned int)h) << 16);
}

// async global->LDS, 16B per lane. LDS dest must be wave-uniform base + lane*16.
__device__ __forceinline__ void gld_lds16(const void* g, void* l) {
    __builtin_amdgcn_global_load_lds(
        (const __attribute__((address_space(1))) unsigned int*)g,
        (__attribute__((address_space(3))) unsigned int*)l, 16, 0, 0);
}

// ---------------- fp32 -> bf16 conversion (3 arrays, one launch) ------------
__global__ void cvt3_f32_bf16(const float* __restrict__ a, u16* __restrict__ oa, int na,
                              const float* __restrict__ b, u16* __restrict__ ob, int nb,
                              const float* __restrict__ c, u16* __restrict__ oc, int nc) {
    int i = blockIdx.x * 256 + threadIdx.x;
    const float* in; u16* out;
    if (i < na) { in = a; out = oa; }
    else if (i < na + nb) { in = b; out = ob; i -= na; }
    else if (i < na + nb + nc) { in = c; out = oc; i -= na + nb; }
    else return;
    float4 v = ((const float4*)in)[i];
    u16x4 o;
    o.x = f2bf(v.x); o.y = f2bf(v.y); o.z = f2bf(v.z); o.w = f2bf(v.w);
    ((u16x4*)out)[i] = o;
}

// ---------------- GEMM: C[M,N] = A[M,K] * B[N,K]^T (m97 structure) ----------
template <int OUT_F32>
__global__ __launch_bounds__(256) void gemm_bt(const u16* __restrict__ A,
                                               const u16* __restrict__ B,
                                               void* __restrict__ Cv,
                                               int M, int N, int K) {
    __shared__ u16 As[128 * 32];
    __shared__ u16 Bs[128 * 32];
    const int t = threadIdx.x;
    const int lane = t & 63;
    const int wave = t >> 6;
    const int l16 = lane & 15;
    const int quad = lane >> 4;
    const int bm = blockIdx.x * 128;
    const int bn = blockIdx.y * 128;
    const int wm = (wave & 1) * 64;
    const int wn = (wave >> 1) * 64;
    const int srow = t >> 2;
    const int scol = (t & 3) * 8;

    f32x4 acc[4][4] = {};

    const u16* Ab = A + (size_t)(bm + srow) * K + scol;
    const u16* Bb = B + (size_t)(bn + srow) * K + scol;

    for (int k0 = 0; k0 < K; k0 += 32) {
        gld_lds16(Ab + k0,                    (char*)As + t * 16);
        gld_lds16(Ab + (size_t)64 * K + k0,   (char*)As + 4096 + t * 16);
        gld_lds16(Bb + k0,                    (char*)Bs + t * 16);
        gld_lds16(Bb + (size_t)64 * K + k0,   (char*)Bs + 4096 + t * 16);
        __syncthreads();

        bf16x8 af[4], bf[4];
#pragma unroll
        for (int i = 0; i < 4; i++) {
            af[i] = *(const bf16x8*)&As[(wm + i * 16 + l16) * 32 + quad * 8];
            bf[i] = *(const bf16x8*)&Bs[(wn + i * 16 + l16) * 32 + quad * 8];
        }
#pragma unroll
        for (int i = 0; i < 4; i++)
#pragma unroll
            for (int j = 0; j < 4; j++)
                acc[i][j] = __builtin_amdgcn_mfma_f32_16x16x32_bf16(af[i], bf[j], acc[i][j], 0, 0, 0);
        __syncthreads();
    }

#pragma unroll
    for (int i = 0; i < 4; i++)
#pragma unroll
        for (int j = 0; j < 4; j++)
#pragma unroll
            for (int r = 0; r < 4; r++) {
                const int gm = bm + wm + i * 16 + quad * 4 + r;
                const int gn = bn + wn + j * 16 + l16;
                if (OUT_F32)
                    ((float*)Cv)[(size_t)gm * N + gn] = acc[i][j][r];
                else
                    ((u16*)Cv)[(size_t)gm * N + gn] = f2bf(acc[i][j][r]);
            }
}

// ---------------- RoPE + scatter: Q,K natural (bf16); V transposed per head (f16) --
// XCD-swizzled 1D grid: head bh runs on XCD bh>>3 — warms the L2 flash will read.
__global__ __launch_bounds__(256) void rope_scatter(const u16* __restrict__ qkv,
                                                    const float* __restrict__ cosT,
                                                    const float* __restrict__ sinT,
                                                    u16* __restrict__ Qb,
                                                    u16* __restrict__ Kb,
                                                    f16* __restrict__ Vtg) {
    __shared__ f16 Vt[64 * 64];
    const int tid = threadIdx.x;
    const int i = blockIdx.x;                 // 0..2047
    const int xcd = i & 7, w = i >> 3;        // w: 0..255
    const int bh = xcd * 8 + (w >> 5);        // 8 heads per XCD
    const int b = bh >> 4, h = bh & 15;
    const int t0 = (w & 31) * 64;
    const int tloc = tid >> 2;         // 0..63
    const int p = tid & 3;             // 16-wide d segment
    const int ta = t0 + tloc;
    const size_t rowb = ((size_t)b * Tq + ta) * (3 * Dq) + h * 64;
    const int lo = (p & 1) * 16;

    union U16 { u16x8 v[2]; u16 a[16]; };
    U16 qlo, qhi, klo, khi, vv;
    qlo.v[0] = *(const u16x8*)(qkv + rowb + lo);
    qlo.v[1] = *(const u16x8*)(qkv + rowb + lo + 8);
    qhi.v[0] = *(const u16x8*)(qkv + rowb + lo + 32);
    qhi.v[1] = *(const u16x8*)(qkv + rowb + lo + 40);
    klo.v[0] = *(const u16x8*)(qkv + rowb + Dq + lo);
    klo.v[1] = *(const u16x8*)(qkv + rowb + Dq + lo + 8);
    khi.v[0] = *(const u16x8*)(qkv + rowb + Dq + lo + 32);
    khi.v[1] = *(const u16x8*)(qkv + rowb + Dq + lo + 40);
    vv.v[0]  = *(const u16x8*)(qkv + rowb + 2 * Dq + p * 16);
    vv.v[1]  = *(const u16x8*)(qkv + rowb + 2 * Dq + p * 16 + 8);

    float cc[16], ss[16];
    {
        const float4* c4 = (const float4*)(cosT + (size_t)ta * 32 + lo);
        const float4* s4 = (const float4*)(sinT + (size_t)ta * 32 + lo);
#pragma unroll
        for (int e = 0; e < 4; e++) {
            float4 c = c4[e], s = s4[e];
            cc[e * 4 + 0] = c.x; cc[e * 4 + 1] = c.y; cc[e * 4 + 2] = c.z; cc[e * 4 + 3] = c.w;
            ss[e * 4 + 0] = s.x; ss[e * 4 + 1] = s.y; ss[e * 4 + 2] = s.z; ss[e * 4 + 3] = s.w;
        }
    }

    U16 qo, ko;
    const bool first = (p < 2);
#pragma unroll
    for (int e = 0; e < 16; e++) {
        const float q1 = bf2f(qlo.a[e]), q2 = bf2f(qhi.a[e]);
        const float k1 = bf2f(klo.a[e]), k2 = bf2f(khi.a[e]);
        const float qv = first ? (q1 * cc[e] - q2 * ss[e]) : (q1 * ss[e] + q2 * cc[e]);
        const float kv = first ? (k1 * cc[e] - k2 * ss[e]) : (k1 * ss[e] + k2 * cc[e]);
        qo.a[e] = f2bf(qv * 0.18033688011112042f);  // 0.125 * log2(e)
        ko.a[e] = f2bf(kv);
    }
    const size_t qrow = ((size_t)bh * Tq + ta) * 64 + p * 16;
    *(u16x8*)(Qb + qrow)     = qo.v[0];
    *(u16x8*)(Qb + qrow + 8) = qo.v[1];
    *(u16x8*)(Kb + qrow)     = ko.v[0];
    *(u16x8*)(Kb + qrow + 8) = ko.v[1];

    // V -> LDS transposed, chunk-rotated: element (d, tloc) at chunk pos (tloc>>3)^rot(d)
#pragma unroll
    for (int e = 0; e < 16; e++) {
        const int d = p * 16 + e;
        const int pc = (tloc >> 3) ^ ((d + (d >> 4)) & 7);
        Vt[d * 64 + pc * 8 + (tloc & 7)] = (f16)bf2f(vv.a[e]);
    }
    __syncthreads();
    const int drow = tid >> 2, tseg = tid & 3;
    const int rot = (drow + (drow >> 4)) & 7;
    f16x8v r0 = *(const f16x8v*)&Vt[drow * 64 + ((2 * tseg) ^ rot) * 8];
    f16x8v r1 = *(const f16x8v*)&Vt[drow * 64 + ((2 * tseg + 1) ^ rot) * 8];
    f16* vout = Vtg + ((size_t)bh * 64 + drow) * Tq + t0 + tseg * 16;
    *(f16x8v*)vout = r0;
    *(f16x8v*)(vout + 8) = r1;
}

// ---------------- flash attention: S^T form, constant-max softmax -----------
template <bool MASK>
__device__ __forceinline__ void flash_tile(const u16* __restrict__ Ks,
                                           const f16* __restrict__ Vs,
                                           const bf16x8& qf0, const bf16x8& qf1,
                                           int l16, int quad, int i_loc,
                                           float& l_run, f32x4* o_acc) {
    f32x4 s[4];
    const int cp0 = quad ^ (l16 & 7);
    const int cp1 = (4 + quad) ^ (l16 & 7);
#pragma unroll
    for (int tn = 0; tn < 4; tn++) {
        const int jrow = tn * 16 + l16;
        bf16x8 kf0 = *(const bf16x8*)&Ks[jrow * 64 + cp0 * 8];
        bf16x8 kf1 = *(const bf16x8*)&Ks[jrow * 64 + cp1 * 8];
        f32x4 z = {0.f, 0.f, 0.f, 0.f};
        z = __builtin_amdgcn_mfma_f32_16x16x32_bf16(kf0, qf0, z, 0, 0, 0);
        z = __builtin_amdgcn_mfma_f32_16x16x32_bf16(kf1, qf1, z, 0, 0, 0);
        s[tn] = z;
    }
    float rsa[4];
#pragma unroll
    for (int tn = 0; tn < 4; tn++) {
        float rs = 0.f;
#pragma unroll
        for (int r = 0; r < 4; r++) {
            float v = s[tn][r];
            if (MASK) {
                const int j_loc = tn * 16 + quad * 4 + r;
                if (j_loc > i_loc) v = -1e30f;     // causal mask
            }
            float p = exp2f(v);
            rs += p;                               // l includes the diagonal...
            if (MASK) {
                const int j_loc = tn * 16 + quad * 4 + r;
                if (j_loc == i_loc) p = 0.f;       // ...PV excludes it (== out - self_w*v)
            }
            s[tn][r] = p;
        }
        rsa[tn] = rs;
    }
    l_run += (rsa[0] + rsa[1]) + (rsa[2] + rsa[3]);

    f16x4 pf[4];
#pragma unroll
    for (int tk = 0; tk < 4; tk++)
        pf[tk] = f16x4{(f16)s[tk][0], (f16)s[tk][1], (f16)s[tk][2], (f16)s[tk][3]};
#pragma unroll
    for (int td = 0; td < 4; td++) {
        const int drow = td * 16 + l16;
#pragma unroll
        for (int tk = 0; tk < 4; tk++) {
            const int cp = (2 * tk + (quad >> 1)) ^ (l16 & 7);
            f16x4 vf = *(const f16x4*)&Vs[drow * 64 + cp * 8 + (quad & 1) * 4];
            o_acc[td] = __builtin_amdgcn_mfma_f32_16x16x16f16(vf, pf[tk], o_acc[td], 0, 0, 0);
        }
    }
}

// 512 threads = 8 waves; 128 queries/block; 64-key K/V tiles double-buffered.
// 1D grid 1024, XCD-swizzled: head bh entirely on XCD bh>>3 (KV set = 4MB = L2);
// consecutive blocks take complementary q-tiles (x, 15-x) for per-CU balance.
__global__ __launch_bounds__(512, 8) void flash(const u16* __restrict__ Qb,
                                                const u16* __restrict__ Kb,
                                                const f16* __restrict__ Vtg,
                                                u16* __restrict__ Ob) {
    __shared__ __align__(16) char smem[32768];   // 2 x (K 8KB + V 8KB)

    const int t = threadIdx.x, lane = t & 63, wave = t >> 6;
    const int l16 = lane & 15, quad = lane >> 4;
    const int i = blockIdx.x;                    // 0..1023
    const int xcd = i & 7, w = i >> 3;           // w: 0..127
    const int bh = xcd * 8 + (w >> 4);           // 8 heads per XCD
    const int b = bh >> 4, h = bh & 15;
    const int pr = (w >> 1) & 7;
    const int x = (w & 1) ? pr : 15 - pr;        // complementary pairs: work ~const
    const int q0 = x * 128;
    const u16* Qp = Qb + (size_t)bh * Tq * 64;
    const u16* Kp = Kb + (size_t)bh * Tq * 64;
    const f16* Vp = Vtg + (size_t)bh * 64 * Tq;

    const int i_abs = q0 + wave * 16 + l16;
    bf16x8 qf0 = *(const bf16x8*)(Qp + (size_t)i_abs * 64 + quad * 8);
    bf16x8 qf1 = *(const bf16x8*)(Qp + (size_t)i_abs * 64 + 32 + quad * 8);
    // pin Q-frag loads complete so manual vmcnt bookkeeping below is exact
    asm volatile("s_waitcnt vmcnt(0)" : "+v"(qf0), "+v"(qf1) :: "memory");

    float l_run = 0.f;
    f32x4 o_acc[4] = {};

    const int srow = t >> 3;                     // 0..63 (512 threads)
    const int sc = (t & 7) ^ (srow & 7);         // swizzled chunk slot
    const int diag_n = (q0 >> 6) + (wave >> 2);  // this wave's diagonal tile
    const int i_tloc = (wave & 3) * 16 + l16;    // query pos within that tile
    const int nt = (q0 >> 6) + 2;

    auto stage = [&](int n, char* buf) {         // 2 loads -> vmcnt +2
        const int j0 = n * 64;
        gld_lds16(Kp + (size_t)(j0 + srow) * 64 + sc * 8, buf + t * 16);
        gld_lds16(Vp + (size_t)srow * Tq + j0 + sc * 8,   buf + 8192 + t * 16);
    };

    stage(0, smem);
    for (int n = 0; n < nt; n++) {
        char* cur = smem + (n & 1) * 16384;
        if (n + 1 < nt) {
            stage(n + 1, smem + ((n + 1) & 1) * 16384);
            asm volatile("s_waitcnt vmcnt(2)\n\ts_barrier" ::: "memory");
        } else {
            asm volatile("s_waitcnt vmcnt(0)\n\ts_barrier" ::: "memory");
        }
        const u16* Ks = (const u16*)cur;
        const f16* Vs = (const f16*)(cur + 8192);
        if (n < diag_n)
            flash_tile<false>(Ks, Vs, qf0, qf1, l16, quad, i_tloc, l_run, o_acc);
        else if (n == diag_n)
            flash_tile<true>(Ks, Vs, qf0, qf1, l16, quad, i_tloc, l_run, o_acc);
        // waves with n > diag_n skip compute but still hit the barriers
        asm volatile("s_barrier" ::: "memory");
    }

    // reduce l across the 4 quads sharing each query (once, not per tile)
    l_run += __shfl_xor(l_run, 16, 64);
    l_run += __shfl_xor(l_run, 32, 64);
    const float inv_l = 1.f / l_run;

    // epilogue: O^T -> O via padded LDS (stride 72), coalesced bf16 stores
    u16* Os = (u16*)smem;                        // 8 waves * 16 * 72 u16 = 18KB
#pragma unroll
    for (int td = 0; td < 4; td++) {
        u16x4 o;
#pragma unroll
        for (int r = 0; r < 4; r++) o[r] = f2bf(o_acc[td][r] * inv_l);
        *(u16x4*)&Os[wave * 1152 + l16 * 72 + td * 16 + quad * 4] = o;
    }
    __syncthreads();
    const int oi = lane >> 2, od = (lane & 3) * 16;
    u16x8 r0 = *(const u16x8*)&Os[wave * 1152 + oi * 72 + od];
    u16x8 r1 = *(const u16x8*)&Os[wave * 1152 + oi * 72 + od + 8];
    const size_t orow = ((size_t)b * Tq + q0 + wave * 16 + oi) * Dq + h * 64 + od;
    *(u16x8*)&Ob[orow] = r0;
    *(u16x8*)&Ob[orow + 8] = r1;
}

// ---------------- launch ----------------
extern "C" void kernel_launch(void* const* d_in, const int* in_sizes, int n_in,
                              void* d_out, int out_size, void* d_ws, size_t ws_size,
                              hipStream_t stream) {
    const float* x     = (const float*)d_in[0];
    const float* cosT  = (const float*)d_in[1];
    const float* sinT  = (const float*)d_in[2];
    const float* Wqkv  = (const float*)d_in[3];
    const float* Wproj = (const float*)d_in[4];

    u16* xb     = (u16*)d_ws;                          // 8192*1024
    u16* wqkvb  = xb + (size_t)8192 * 1024;            // 3072*1024
    u16* wprojb = wqkvb + (size_t)3072 * 1024;         // 1024*1024
    u16* qkv    = wprojb + (size_t)1024 * 1024;        // 8192*3072
    u16* Qb     = qkv + (size_t)8192 * 3072;           // 64*2048*64
    u16* Kb     = Qb + (size_t)64 * 2048 * 64;         // 64*2048*64
    f16* Vtg    = (f16*)(Kb + (size_t)64 * 2048 * 64); // 64*64*2048 (per-head transposed)
    u16* attn   = qkv;                                 // reuse: qkv dead after rope

    cvt3_f32_bf16<<<12288, 256, 0, stream>>>(x, xb, 2097152,
                                             Wqkv, wqkvb, 786432,
                                             Wproj, wprojb, 262144);

    gemm_bt<0><<<dim3(64, 24), 256, 0, stream>>>(xb, wqkvb, (void*)qkv, 8192, 3072, 1024);
    rope_scatter<<<2048, 256, 0, stream>>>(qkv, cosT, sinT, Qb, Kb, Vtg);
    flash<<<1024, 512, 0, stream>>>(Qb, Kb, Vtg, attn);
    gemm_bt<1><<<dim3(64, 8), 256, 0, stream>>>(attn, wprojb, d_out, 8192, 1024, 1024);
}

// Round 7
// 277.624 us; speedup vs baseline: 1.4262x; 1.4262x over previous
//
#include <hip/hip_runtime.h>

constexpr int Tq = 2048;
constexpr int Dq = 1024;

typedef __bf16 bf16x8 __attribute__((ext_vector_type(8)));
typedef float f32x4 __attribute__((ext_vector_type(4)));
typedef _Float16 f16;
typedef f16 f16x4 __attribute__((ext_vector_type(4)));
typedef f16 f16x8v __attribute__((ext_vector_type(8)));
typedef unsigned short u16;
typedef u16 u16x4 __attribute__((ext_vector_type(4)));
typedef u16 u16x8 __attribute__((ext_vector_type(8)));

__device__ __forceinline__ u16 f2bf(float f) {
    unsigned int u = __float_as_uint(f);
    u += 0x7fffu + ((u >> 16) & 1u);   // RNE
    return (u16)(u >> 16);
}
__device__ __forceinline__ float bf2f(u16 h) {
    return __uint_as_float(((unsigned int)h) << 16);
}

// async global->LDS, 16B per lane. LDS dest must be wave-uniform base + lane*16.
__device__ __forceinline__ void gld_lds16(const void* g, void* l) {
    __builtin_amdgcn_global_load_lds(
        (const __attribute__((address_space(1))) unsigned int*)g,
        (__attribute__((address_space(3))) unsigned int*)l, 16, 0, 0);
}

// ---------------- fp32 -> bf16 conversion (3 arrays, one launch) ------------
__global__ void cvt3_f32_bf16(const float* __restrict__ a, u16* __restrict__ oa, int na,
                              const float* __restrict__ b, u16* __restrict__ ob, int nb,
                              const float* __restrict__ c, u16* __restrict__ oc, int nc) {
    int i = blockIdx.x * 256 + threadIdx.x;
    const float* in; u16* out;
    if (i < na) { in = a; out = oa; }
    else if (i < na + nb) { in = b; out = ob; i -= na; }
    else if (i < na + nb + nc) { in = c; out = oc; i -= na + nb; }
    else return;
    float4 v = ((const float4*)in)[i];
    u16x4 o;
    o.x = f2bf(v.x); o.y = f2bf(v.y); o.z = f2bf(v.z); o.w = f2bf(v.w);
    ((u16x4*)out)[i] = o;
}

// ---------------- GEMM: C[M,N] = A[M,K] * B[N,K]^T (m97 structure) ----------
template <int OUT_F32>
__global__ __launch_bounds__(256) void gemm_bt(const u16* __restrict__ A,
                                               const u16* __restrict__ B,
                                               void* __restrict__ Cv,
                                               int M, int N, int K) {
    __shared__ u16 As[128 * 32];
    __shared__ u16 Bs[128 * 32];
    const int t = threadIdx.x;
    const int lane = t & 63;
    const int wave = t >> 6;
    const int l16 = lane & 15;
    const int quad = lane >> 4;
    const int bm = blockIdx.x * 128;
    const int bn = blockIdx.y * 128;
    const int wm = (wave & 1) * 64;
    const int wn = (wave >> 1) * 64;
    const int srow = t >> 2;
    const int scol = (t & 3) * 8;

    f32x4 acc[4][4] = {};

    const u16* Ab = A + (size_t)(bm + srow) * K + scol;
    const u16* Bb = B + (size_t)(bn + srow) * K + scol;

    for (int k0 = 0; k0 < K; k0 += 32) {
        gld_lds16(Ab + k0,                    (char*)As + t * 16);
        gld_lds16(Ab + (size_t)64 * K + k0,   (char*)As + 4096 + t * 16);
        gld_lds16(Bb + k0,                    (char*)Bs + t * 16);
        gld_lds16(Bb + (size_t)64 * K + k0,   (char*)Bs + 4096 + t * 16);
        __syncthreads();

        bf16x8 af[4], bf[4];
#pragma unroll
        for (int i = 0; i < 4; i++) {
            af[i] = *(const bf16x8*)&As[(wm + i * 16 + l16) * 32 + quad * 8];
            bf[i] = *(const bf16x8*)&Bs[(wn + i * 16 + l16) * 32 + quad * 8];
        }
#pragma unroll
        for (int i = 0; i < 4; i++)
#pragma unroll
            for (int j = 0; j < 4; j++)
                acc[i][j] = __builtin_amdgcn_mfma_f32_16x16x32_bf16(af[i], bf[j], acc[i][j], 0, 0, 0);
        __syncthreads();
    }

#pragma unroll
    for (int i = 0; i < 4; i++)
#pragma unroll
        for (int j = 0; j < 4; j++)
#pragma unroll
            for (int r = 0; r < 4; r++) {
                const int gm = bm + wm + i * 16 + quad * 4 + r;
                const int gn = bn + wn + j * 16 + l16;
                if (OUT_F32)
                    ((float*)Cv)[(size_t)gm * N + gn] = acc[i][j][r];
                else
                    ((u16*)Cv)[(size_t)gm * N + gn] = f2bf(acc[i][j][r]);
            }
}

// ---------------- RoPE + scatter: Q,K natural (bf16); V transposed per head (f16) --
// XCD-swizzled 1D grid: head bh runs on XCD bh>>3 — warms the L2 flash will read.
__global__ __launch_bounds__(256) void rope_scatter(const u16* __restrict__ qkv,
                                                    const float* __restrict__ cosT,
                                                    const float* __restrict__ sinT,
                                                    u16* __restrict__ Qb,
                                                    u16* __restrict__ Kb,
                                                    f16* __restrict__ Vtg) {
    __shared__ f16 Vt[64 * 64];
    const int tid = threadIdx.x;
    const int i = blockIdx.x;                 // 0..2047
    const int xcd = i & 7, w = i >> 3;        // w: 0..255
    const int bh = xcd * 8 + (w >> 5);        // 8 heads per XCD
    const int b = bh >> 4, h = bh & 15;
    const int t0 = (w & 31) * 64;
    const int tloc = tid >> 2;         // 0..63
    const int p = tid & 3;             // 16-wide d segment
    const int ta = t0 + tloc;
    const size_t rowb = ((size_t)b * Tq + ta) * (3 * Dq) + h * 64;
    const int lo = (p & 1) * 16;

    union U16 { u16x8 v[2]; u16 a[16]; };
    U16 qlo, qhi, klo, khi, vv;
    qlo.v[0] = *(const u16x8*)(qkv + rowb + lo);
    qlo.v[1] = *(const u16x8*)(qkv + rowb + lo + 8);
    qhi.v[0] = *(const u16x8*)(qkv + rowb + lo + 32);
    qhi.v[1] = *(const u16x8*)(qkv + rowb + lo + 40);
    klo.v[0] = *(const u16x8*)(qkv + rowb + Dq + lo);
    klo.v[1] = *(const u16x8*)(qkv + rowb + Dq + lo + 8);
    khi.v[0] = *(const u16x8*)(qkv + rowb + Dq + lo + 32);
    khi.v[1] = *(const u16x8*)(qkv + rowb + Dq + lo + 40);
    vv.v[0]  = *(const u16x8*)(qkv + rowb + 2 * Dq + p * 16);
    vv.v[1]  = *(const u16x8*)(qkv + rowb + 2 * Dq + p * 16 + 8);

    float cc[16], ss[16];
    {
        const float4* c4 = (const float4*)(cosT + (size_t)ta * 32 + lo);
        const float4* s4 = (const float4*)(sinT + (size_t)ta * 32 + lo);
#pragma unroll
        for (int e = 0; e < 4; e++) {
            float4 c = c4[e], s = s4[e];
            cc[e * 4 + 0] = c.x; cc[e * 4 + 1] = c.y; cc[e * 4 + 2] = c.z; cc[e * 4 + 3] = c.w;
            ss[e * 4 + 0] = s.x; ss[e * 4 + 1] = s.y; ss[e * 4 + 2] = s.z; ss[e * 4 + 3] = s.w;
        }
    }

    U16 qo, ko;
    const bool first = (p < 2);
#pragma unroll
    for (int e = 0; e < 16; e++) {
        const float q1 = bf2f(qlo.a[e]), q2 = bf2f(qhi.a[e]);
        const float k1 = bf2f(klo.a[e]), k2 = bf2f(khi.a[e]);
        const float qv = first ? (q1 * cc[e] - q2 * ss[e]) : (q1 * ss[e] + q2 * cc[e]);
        const float kv = first ? (k1 * cc[e] - k2 * ss[e]) : (k1 * ss[e] + k2 * cc[e]);
        qo.a[e] = f2bf(qv * 0.18033688011112042f);  // 0.125 * log2(e)
        ko.a[e] = f2bf(kv);
    }
    const size_t qrow = ((size_t)bh * Tq + ta) * 64 + p * 16;
    *(u16x8*)(Qb + qrow)     = qo.v[0];
    *(u16x8*)(Qb + qrow + 8) = qo.v[1];
    *(u16x8*)(Kb + qrow)     = ko.v[0];
    *(u16x8*)(Kb + qrow + 8) = ko.v[1];

    // V -> LDS transposed, chunk-rotated: element (d, tloc) at chunk pos (tloc>>3)^rot(d)
#pragma unroll
    for (int e = 0; e < 16; e++) {
        const int d = p * 16 + e;
        const int pc = (tloc >> 3) ^ ((d + (d >> 4)) & 7);
        Vt[d * 64 + pc * 8 + (tloc & 7)] = (f16)bf2f(vv.a[e]);
    }
    __syncthreads();
    const int drow = tid >> 2, tseg = tid & 3;
    const int rot = (drow + (drow >> 4)) & 7;
    f16x8v r0 = *(const f16x8v*)&Vt[drow * 64 + ((2 * tseg) ^ rot) * 8];
    f16x8v r1 = *(const f16x8v*)&Vt[drow * 64 + ((2 * tseg + 1) ^ rot) * 8];
    f16* vout = Vtg + ((size_t)bh * 64 + drow) * Tq + t0 + tseg * 16;
    *(f16x8v*)vout = r0;
    *(f16x8v*)(vout + 8) = r1;
}

// ---------------- flash attention: S^T form, constant-max softmax -----------
template <bool MASK>
__device__ __forceinline__ void flash_tile(const u16* __restrict__ Ks,
                                           const f16* __restrict__ Vs,
                                           const bf16x8& qf0, const bf16x8& qf1,
                                           int l16, int quad, int i_loc,
                                           float& l_run, f32x4* o_acc) {
    f32x4 s[4];
    const int cp0 = quad ^ (l16 & 7);
    const int cp1 = (4 + quad) ^ (l16 & 7);
#pragma unroll
    for (int tn = 0; tn < 4; tn++) {
        const int jrow = tn * 16 + l16;
        bf16x8 kf0 = *(const bf16x8*)&Ks[jrow * 64 + cp0 * 8];
        bf16x8 kf1 = *(const bf16x8*)&Ks[jrow * 64 + cp1 * 8];
        f32x4 z = {0.f, 0.f, 0.f, 0.f};
        z = __builtin_amdgcn_mfma_f32_16x16x32_bf16(kf0, qf0, z, 0, 0, 0);
        z = __builtin_amdgcn_mfma_f32_16x16x32_bf16(kf1, qf1, z, 0, 0, 0);
        s[tn] = z;
    }
    float rsa[4];
#pragma unroll
    for (int tn = 0; tn < 4; tn++) {
        float rs = 0.f;
#pragma unroll
        for (int r = 0; r < 4; r++) {
            float v = s[tn][r];
            if (MASK) {
                const int j_loc = tn * 16 + quad * 4 + r;
                if (j_loc > i_loc) v = -1e30f;     // causal mask
            }
            float p = exp2f(v);
            rs += p;                               // l includes the diagonal...
            if (MASK) {
                const int j_loc = tn * 16 + quad * 4 + r;
                if (j_loc == i_loc) p = 0.f;       // ...PV excludes it (== out - self_w*v)
            }
            s[tn][r] = p;
        }
        rsa[tn] = rs;
    }
    l_run += (rsa[0] + rsa[1]) + (rsa[2] + rsa[3]);

    f16x4 pf[4];
#pragma unroll
    for (int tk = 0; tk < 4; tk++)
        pf[tk] = f16x4{(f16)s[tk][0], (f16)s[tk][1], (f16)s[tk][2], (f16)s[tk][3]};
#pragma unroll
    for (int td = 0; td < 4; td++) {
        const int drow = td * 16 + l16;
#pragma unroll
        for (int tk = 0; tk < 4; tk++) {
            const int cp = (2 * tk + (quad >> 1)) ^ (l16 & 7);
            f16x4 vf = *(const f16x4*)&Vs[drow * 64 + cp * 8 + (quad & 1) * 4];
            o_acc[td] = __builtin_amdgcn_mfma_f32_16x16x16f16(vf, pf[tk], o_acc[td], 0, 0, 0);
        }
    }
}

// 512 threads = 8 waves. In-block complementary q-tiles: waves 0-3 own tile x,
// waves 4-7 own tile 31-x  => per-block work = 33 wave-tiles, constant for all
// blocks; each SIMD hosts one short + one long wave (scheduler-proof balance).
// 4-deep LDS ring (64KB) => ONE barrier per tile, prefetch depth 2.
// XCD-swizzled: head bh entirely on XCD bh>>3 (KV working set = 4MB = L2).
__global__ __launch_bounds__(512, 4) void flash(const u16* __restrict__ Qb,
                                                const u16* __restrict__ Kb,
                                                const f16* __restrict__ Vtg,
                                                u16* __restrict__ Ob) {
    __shared__ __align__(16) char smem[65536];   // 4 x (K 8KB + V 8KB)

    const int t = threadIdx.x, lane = t & 63, wave = t >> 6;
    const int l16 = lane & 15, quad = lane >> 4;
    const int i = blockIdx.x;                    // 0..1023
    const int xcd = i & 7, w = i >> 3;           // w: 0..127
    const int bh = xcd * 8 + (w >> 4);           // 8 heads per XCD
    const int b = bh >> 4, h = bh & 15;
    const int x = w & 15;
    const int qt = (wave < 4) ? x : (31 - x);    // this wave's 64-query tile
    const int q0w = qt * 64;
    const u16* Qp = Qb + (size_t)bh * Tq * 64;
    const u16* Kp = Kb + (size_t)bh * Tq * 64;
    const f16* Vp = Vtg + (size_t)bh * 64 * Tq;

    const int i_abs = q0w + (wave & 3) * 16 + l16;
    bf16x8 qf0 = *(const bf16x8*)(Qp + (size_t)i_abs * 64 + quad * 8);
    bf16x8 qf1 = *(const bf16x8*)(Qp + (size_t)i_abs * 64 + 32 + quad * 8);
    // pin Q-frag loads complete so manual vmcnt bookkeeping below is exact
    asm volatile("s_waitcnt vmcnt(0)" : "+v"(qf0), "+v"(qf1) :: "memory");

    float l_run = 0.f;
    f32x4 o_acc[4] = {};

    const int srow = t >> 3;                     // 0..63 (512 threads)
    const int sc = (t & 7) ^ (srow & 7);         // swizzled chunk slot
    const int diag_n = qt;                       // this wave's diagonal tile
    const int i_tloc = (wave & 3) * 16 + l16;    // query pos within the tile
    const int nt = 32 - x;                       // tiles 0 .. 31-x  (nt >= 17)

    auto stage = [&](int n) {                    // 2 loads -> vmcnt +2
        const int j0 = n * 64;
        char* buf = smem + (n & 3) * 16384;
        gld_lds16(Kp + (size_t)(j0 + srow) * 64 + sc * 8, buf + t * 16);
        gld_lds16(Vp + (size_t)srow * Tq + j0 + sc * 8,   buf + 8192 + t * 16);
    };

    stage(0);
    stage(1);
    for (int n = 0; n < nt; n++) {
        char* cur = smem + (n & 3) * 16384;
        if (n + 2 < nt) {
            stage(n + 2);
            // ring depth 4: stage(n+2) overwrites the buffer last read at
            // compute(n-2), which barrier(n-1) already ordered => safe with a
            // single barrier per tile. Wait leaves tiles n+1, n+2 in flight.
            asm volatile("s_waitcnt vmcnt(4)\n\ts_barrier" ::: "memory");
        } else if (n + 1 < nt) {
            asm volatile("s_waitcnt vmcnt(2)\n\ts_barrier" ::: "memory");
        } else {
            asm volatile("s_waitcnt vmcnt(0)\n\ts_barrier" ::: "memory");
        }
        const u16* Ks = (const u16*)cur;
        const f16* Vs = (const f16*)(cur + 8192);
        if (n < diag_n)
            flash_tile<false>(Ks, Vs, qf0, qf1, l16, quad, i_tloc, l_run, o_acc);
        else if (n == diag_n)
            flash_tile<true>(Ks, Vs, qf0, qf1, l16, quad, i_tloc, l_run, o_acc);
        // waves with n > diag_n skip compute but still hit the barrier
    }

    // reduce l across the 4 quads sharing each query (once, not per tile)
    l_run += __shfl_xor(l_run, 16, 64);
    l_run += __shfl_xor(l_run, 32, 64);
    const float inv_l = 1.f / l_run;

    // epilogue: O^T -> O via padded LDS (stride 72), coalesced bf16 stores
    __syncthreads();                             // all waves done reading ring
    u16* Os = (u16*)smem;                        // 8 waves * 16 * 72 u16 = 18KB
#pragma unroll
    for (int td = 0; td < 4; td++) {
        u16x4 o;
#pragma unroll
        for (int r = 0; r < 4; r++) o[r] = f2bf(o_acc[td][r] * inv_l);
        *(u16x4*)&Os[wave * 1152 + l16 * 72 + td * 16 + quad * 4] = o;
    }
    __syncthreads();
    const int oi = lane >> 2, od = (lane & 3) * 16;
    u16x8 r0 = *(const u16x8*)&Os[wave * 1152 + oi * 72 + od];
    u16x8 r1 = *(const u16x8*)&Os[wave * 1152 + oi * 72 + od + 8];
    const size_t orow = ((size_t)b * Tq + q0w + (wave & 3) * 16 + oi) * Dq + h * 64 + od;
    *(u16x8*)&Ob[orow] = r0;
    *(u16x8*)&Ob[orow + 8] = r1;
}

// ---------------- launch ----------------
extern "C" void kernel_launch(void* const* d_in, const int* in_sizes, int n_in,
                              void* d_out, int out_size, void* d_ws, size_t ws_size,
                              hipStream_t stream) {
    const float* x     = (const float*)d_in[0];
    const float* cosT  = (const float*)d_in[1];
    const float* sinT  = (const float*)d_in[2];
    const float* Wqkv  = (const float*)d_in[3];
    const float* Wproj = (const float*)d_in[4];

    u16* xb     = (u16*)d_ws;                          // 8192*1024
    u16* wqkvb  = xb + (size_t)8192 * 1024;            // 3072*1024
    u16* wprojb = wqkvb + (size_t)3072 * 1024;         // 1024*1024
    u16* qkv    = wprojb + (size_t)1024 * 1024;        // 8192*3072
    u16* Qb     = qkv + (size_t)8192 * 3072;           // 64*2048*64
    u16* Kb     = Qb + (size_t)64 * 2048 * 64;         // 64*2048*64
    f16* Vtg    = (f16*)(Kb + (size_t)64 * 2048 * 64); // 64*64*2048 (per-head transposed)
    u16* attn   = qkv;                                 // reuse: qkv dead after rope

    cvt3_f32_bf16<<<12288, 256, 0, stream>>>(x, xb, 2097152,
                                             Wqkv, wqkvb, 786432,
                                             Wproj, wprojb, 262144);

    gemm_bt<0><<<dim3(64, 24), 256, 0, stream>>>(xb, wqkvb, (void*)qkv, 8192, 3072, 1024);
    rope_scatter<<<2048, 256, 0, stream>>>(qkv, cosT, sinT, Qb, Kb, Vtg);
    flash<<<1024, 512, 0, stream>>>(Qb, Kb, Vtg, attn);
    gemm_bt<1><<<dim3(64, 8), 256, 0, stream>>>(attn, wprojb, d_out, 8192, 1024, 1024);
}

// Round 8
// 255.579 us; speedup vs baseline: 1.5492x; 1.0863x over previous
//
#include <hip/hip_runtime.h>

constexpr int Tq = 2048;
constexpr int Dq = 1024;

typedef __bf16 bf16x8 __attribute__((ext_vector_type(8)));
typedef float f32x4 __attribute__((ext_vector_type(4)));
typedef _Float16 f16;
typedef f16 f16x4 __attribute__((ext_vector_type(4)));
typedef unsigned short u16;
typedef u16 u16x4 __attribute__((ext_vector_type(4)));
typedef u16 u16x8 __attribute__((ext_vector_type(8)));

__device__ __forceinline__ u16 f2bf(float f) {
    unsigned int u = __float_as_uint(f);
    u += 0x7fffu + ((u >> 16) & 1u);   // RNE
    return (u16)(u >> 16);
}

// async global->LDS, 16B per lane. LDS dest must be wave-uniform base + lane*16.
__device__ __forceinline__ void gld_lds16(const void* g, void* l) {
    __builtin_amdgcn_global_load_lds(
        (const __attribute__((address_space(1))) unsigned int*)g,
        (__attribute__((address_space(3))) unsigned int*)l, 16, 0, 0);
}

// ---------------- fp32 -> bf16 conversion (3 arrays, one launch) ------------
__global__ void cvt3_f32_bf16(const float* __restrict__ a, u16* __restrict__ oa, int na,
                              const float* __restrict__ b, u16* __restrict__ ob, int nb,
                              const float* __restrict__ c, u16* __restrict__ oc, int nc) {
    int i = blockIdx.x * 256 + threadIdx.x;
    const float* in; u16* out;
    if (i < na) { in = a; out = oa; }
    else if (i < na + nb) { in = b; out = ob; i -= na; }
    else if (i < na + nb + nc) { in = c; out = oc; i -= na + nb; }
    else return;
    float4 v = ((const float4*)in)[i];
    u16x4 o;
    o.x = f2bf(v.x); o.y = f2bf(v.y); o.z = f2bf(v.z); o.w = f2bf(v.w);
    ((u16x4*)out)[i] = o;
}

// ---------------- QKV GEMM with fused RoPE + scatter epilogue ----------------
// C[8192,3072] = xb * Wqkv^T. blockIdx.y: 0..7 -> Q (rope+scale), 8..15 -> K
// (rope), 16..23 -> V (transposed f16). A 128-col tile never straddles Q/K/V,
// and d & d+32 of one head land in the SAME lane (sub-tiles j and j+2).
__global__ __launch_bounds__(256) void gemm_qkv(const u16* __restrict__ A,
                                                const u16* __restrict__ B,
                                                const float* __restrict__ cosT,
                                                const float* __restrict__ sinT,
                                                u16* __restrict__ Qb,
                                                u16* __restrict__ Kb,
                                                f16* __restrict__ Vtg) {
    constexpr int K = 1024, N = 3072;
    __shared__ u16 As[128 * 32];
    __shared__ u16 Bs[128 * 32];
    const int t = threadIdx.x;
    const int lane = t & 63;
    const int wave = t >> 6;
    const int l16 = lane & 15;
    const int quad = lane >> 4;
    const int bm = blockIdx.x * 128;
    const int by = blockIdx.y;
    const int bn = by * 128;
    const int wm = (wave & 1) * 64;
    const int wn = (wave >> 1) * 64;
    const int srow = t >> 2;
    const int scol = (t & 3) * 8;

    f32x4 acc[4][4] = {};

    const u16* Ab = A + (size_t)(bm + srow) * K + scol;
    const u16* Bb = B + (size_t)(bn + srow) * K + scol;

    for (int k0 = 0; k0 < K; k0 += 32) {
        gld_lds16(Ab + k0,                    (char*)As + t * 16);
        gld_lds16(Ab + (size_t)64 * K + k0,   (char*)As + 4096 + t * 16);
        gld_lds16(Bb + k0,                    (char*)Bs + t * 16);
        gld_lds16(Bb + (size_t)64 * K + k0,   (char*)Bs + 4096 + t * 16);
        __syncthreads();

        bf16x8 af[4], bf[4];
#pragma unroll
        for (int i = 0; i < 4; i++) {
            af[i] = *(const bf16x8*)&As[(wm + i * 16 + l16) * 32 + quad * 8];
            bf[i] = *(const bf16x8*)&Bs[(wn + i * 16 + l16) * 32 + quad * 8];
        }
#pragma unroll
        for (int i = 0; i < 4; i++)
#pragma unroll
            for (int j = 0; j < 4; j++)
                acc[i][j] = __builtin_amdgcn_mfma_f32_16x16x32_bf16(af[i], bf[j], acc[i][j], 0, 0, 0);
        __syncthreads();
    }

    const int kind = by >> 3;                   // 0=Q 1=K 2=V
    if (kind < 2) {
        // rope: pairs (j, j+2) give (d, d+32) of head h in the same lane
        u16* Out = kind ? Kb : Qb;
        const float qscale = kind ? 1.f : 0.18033688011112042f;  // 0.125*log2(e)
        const int h = ((by & 7) << 1) + (wn >> 6);
#pragma unroll
        for (int i = 0; i < 4; i++)
#pragma unroll
            for (int r = 0; r < 4; r++) {
                const int gm = bm + wm + i * 16 + quad * 4 + r;
                const int b = gm >> 11, tt = gm & 2047;
                const size_t row = ((size_t)(b * 16 + h) * Tq + tt) * 64;
#pragma unroll
                for (int jj = 0; jj < 2; jj++) {
                    const int dd = jj * 16 + l16;            // 0..31
                    const float c = cosT[tt * 32 + dd];
                    const float s = sinT[tt * 32 + dd];
                    const float v1 = acc[i][jj][r];
                    const float v2 = acc[i][jj + 2][r];
                    Out[row + dd]      = f2bf((v1 * c - v2 * s) * qscale);
                    Out[row + dd + 32] = f2bf((v1 * s + v2 * c) * qscale);
                }
            }
    } else {
        // V: write transposed (bh, d, t) in f16; f16x4 contiguous along t
#pragma unroll
        for (int i = 0; i < 4; i++) {
            const int gm0 = bm + wm + i * 16 + quad * 4;
            const int b = gm0 >> 11, tt = gm0 & 2047;
#pragma unroll
            for (int j = 0; j < 4; j++) {
                const int col = wn + j * 16 + l16;           // 0..127
                const int h = ((by & 7) << 1) + (col >> 6);
                const int d = col & 63;
                f16x4 o = {(f16)acc[i][j][0], (f16)acc[i][j][1],
                           (f16)acc[i][j][2], (f16)acc[i][j][3]};
                *(f16x4*)&Vtg[((size_t)(b * 16 + h) * 64 + d) * Tq + tt] = o;
            }
        }
    }
}

// ---------------- GEMM: C[M,N] = A[M,K] * B[N,K]^T (m97 structure) ----------
__global__ __launch_bounds__(256) void gemm_bt(const u16* __restrict__ A,
                                               const u16* __restrict__ B,
                                               float* __restrict__ Cv,
                                               int M, int N, int K) {
    __shared__ u16 As[128 * 32];
    __shared__ u16 Bs[128 * 32];
    const int t = threadIdx.x;
    const int lane = t & 63;
    const int wave = t >> 6;
    const int l16 = lane & 15;
    const int quad = lane >> 4;
    const int bm = blockIdx.x * 128;
    const int bn = blockIdx.y * 128;
    const int wm = (wave & 1) * 64;
    const int wn = (wave >> 1) * 64;
    const int srow = t >> 2;
    const int scol = (t & 3) * 8;

    f32x4 acc[4][4] = {};

    const u16* Ab = A + (size_t)(bm + srow) * K + scol;
    const u16* Bb = B + (size_t)(bn + srow) * K + scol;

    for (int k0 = 0; k0 < K; k0 += 32) {
        gld_lds16(Ab + k0,                    (char*)As + t * 16);
        gld_lds16(Ab + (size_t)64 * K + k0,   (char*)As + 4096 + t * 16);
        gld_lds16(Bb + k0,                    (char*)Bs + t * 16);
        gld_lds16(Bb + (size_t)64 * K + k0,   (char*)Bs + 4096 + t * 16);
        __syncthreads();

        bf16x8 af[4], bf[4];
#pragma unroll
        for (int i = 0; i < 4; i++) {
            af[i] = *(const bf16x8*)&As[(wm + i * 16 + l16) * 32 + quad * 8];
            bf[i] = *(const bf16x8*)&Bs[(wn + i * 16 + l16) * 32 + quad * 8];
        }
#pragma unroll
        for (int i = 0; i < 4; i++)
#pragma unroll
            for (int j = 0; j < 4; j++)
                acc[i][j] = __builtin_amdgcn_mfma_f32_16x16x32_bf16(af[i], bf[j], acc[i][j], 0, 0, 0);
        __syncthreads();
    }

#pragma unroll
    for (int i = 0; i < 4; i++)
#pragma unroll
        for (int j = 0; j < 4; j++)
#pragma unroll
            for (int r = 0; r < 4; r++) {
                const int gm = bm + wm + i * 16 + quad * 4 + r;
                const int gn = bn + wn + j * 16 + l16;
                Cv[(size_t)gm * N + gn] = acc[i][j][r];
            }
}

// ---------------- flash attention: S^T form, constant-max softmax -----------
template <bool MASK>
__device__ __forceinline__ void flash_tile(const u16* __restrict__ Ks,
                                           const f16* __restrict__ Vs,
                                           const bf16x8& qf0, const bf16x8& qf1,
                                           int l16, int quad, int i_loc,
                                           float& l_run, f32x4* o_acc) {
    f32x4 s[4];
    const int cp0 = quad ^ (l16 & 7);
    const int cp1 = (4 + quad) ^ (l16 & 7);
#pragma unroll
    for (int tn = 0; tn < 4; tn++) {
        const int jrow = tn * 16 + l16;
        bf16x8 kf0 = *(const bf16x8*)&Ks[jrow * 64 + cp0 * 8];
        bf16x8 kf1 = *(const bf16x8*)&Ks[jrow * 64 + cp1 * 8];
        f32x4 z = {0.f, 0.f, 0.f, 0.f};
        z = __builtin_amdgcn_mfma_f32_16x16x32_bf16(kf0, qf0, z, 0, 0, 0);
        z = __builtin_amdgcn_mfma_f32_16x16x32_bf16(kf1, qf1, z, 0, 0, 0);
        s[tn] = z;
    }
    float rsa[4];
#pragma unroll
    for (int tn = 0; tn < 4; tn++) {
        float rs = 0.f;
#pragma unroll
        for (int r = 0; r < 4; r++) {
            float v = s[tn][r];
            if (MASK) {
                const int j_loc = tn * 16 + quad * 4 + r;
                if (j_loc > i_loc) v = -1e30f;     // causal mask
            }
            float p = exp2f(v);
            rs += p;                               // l includes the diagonal...
            if (MASK) {
                const int j_loc = tn * 16 + quad * 4 + r;
                if (j_loc == i_loc) p = 0.f;       // ...PV excludes it (== out - self_w*v)
            }
            s[tn][r] = p;
        }
        rsa[tn] = rs;
    }
    l_run += (rsa[0] + rsa[1]) + (rsa[2] + rsa[3]);

    f16x4 pf[4];
#pragma unroll
    for (int tk = 0; tk < 4; tk++)
        pf[tk] = f16x4{(f16)s[tk][0], (f16)s[tk][1], (f16)s[tk][2], (f16)s[tk][3]};
#pragma unroll
    for (int td = 0; td < 4; td++) {
        const int drow = td * 16 + l16;
#pragma unroll
        for (int tk = 0; tk < 4; tk++) {
            const int cp = (2 * tk + (quad >> 1)) ^ (l16 & 7);
            f16x4 vf = *(const f16x4*)&Vs[drow * 64 + cp * 8 + (quad & 1) * 4];
            o_acc[td] = __builtin_amdgcn_mfma_f32_16x16x16f16(vf, pf[tk], o_acc[td], 0, 0, 0);
        }
    }
}

// 512 threads = 8 waves. In-block complementary q-tiles: waves 0-3 own tile x,
// waves 4-7 own tile 31-x => per-block work = 33 wave-tiles = constant; each
// SIMD hosts one short + one long wave. 4-deep LDS ring, ONE barrier per tile.
// XCD-swizzled: head bh entirely on XCD bh>>3 (KV working set = 4MB = L2).
__global__ __launch_bounds__(512, 4) void flash(const u16* __restrict__ Qb,
                                                const u16* __restrict__ Kb,
                                                const f16* __restrict__ Vtg,
                                                u16* __restrict__ Ob) {
    __shared__ __align__(16) char smem[65536];   // 4 x (K 8KB + V 8KB)

    const int t = threadIdx.x, lane = t & 63, wave = t >> 6;
    const int l16 = lane & 15, quad = lane >> 4;
    const int i = blockIdx.x;                    // 0..1023
    const int xcd = i & 7, w = i >> 3;           // w: 0..127
    const int bh = xcd * 8 + (w >> 4);           // 8 heads per XCD
    const int b = bh >> 4, h = bh & 15;
    const int x = w & 15;
    const int qt = (wave < 4) ? x : (31 - x);    // this wave's 64-query tile
    const int q0w = qt * 64;
    const u16* Qp = Qb + (size_t)bh * Tq * 64;
    const u16* Kp = Kb + (size_t)bh * Tq * 64;
    const f16* Vp = Vtg + (size_t)bh * 64 * Tq;

    const int i_abs = q0w + (wave & 3) * 16 + l16;
    bf16x8 qf0 = *(const bf16x8*)(Qp + (size_t)i_abs * 64 + quad * 8);
    bf16x8 qf1 = *(const bf16x8*)(Qp + (size_t)i_abs * 64 + 32 + quad * 8);
    // pin Q-frag loads complete so manual vmcnt bookkeeping below is exact
    asm volatile("s_waitcnt vmcnt(0)" : "+v"(qf0), "+v"(qf1) :: "memory");

    float l_run = 0.f;
    f32x4 o_acc[4] = {};

    const int srow = t >> 3;                     // 0..63 (512 threads)
    const int sc = (t & 7) ^ (srow & 7);         // swizzled chunk slot
    const int diag_n = qt;                       // this wave's diagonal tile
    const int i_tloc = (wave & 3) * 16 + l16;    // query pos within the tile
    const int nt = 32 - x;                       // tiles 0 .. 31-x  (nt >= 17)

    auto stage = [&](int n) {                    // 2 loads -> vmcnt +2
        const int j0 = n * 64;
        char* buf = smem + (n & 3) * 16384;
        gld_lds16(Kp + (size_t)(j0 + srow) * 64 + sc * 8, buf + t * 16);
        gld_lds16(Vp + (size_t)srow * Tq + j0 + sc * 8,   buf + 8192 + t * 16);
    };

    stage(0);
    stage(1);
    for (int n = 0; n < nt; n++) {
        char* cur = smem + (n & 3) * 16384;
        if (n + 2 < nt) {
            stage(n + 2);
            // ring depth 4: stage(n+2) overwrites the buffer last read at
            // compute(n-2), already ordered by barrier(n-1) => single barrier.
            asm volatile("s_waitcnt vmcnt(4)\n\ts_barrier" ::: "memory");
        } else if (n + 1 < nt) {
            asm volatile("s_waitcnt vmcnt(2)\n\ts_barrier" ::: "memory");
        } else {
            asm volatile("s_waitcnt vmcnt(0)\n\ts_barrier" ::: "memory");
        }
        const u16* Ks = (const u16*)cur;
        const f16* Vs = (const f16*)(cur + 8192);
        if (n < diag_n)
            flash_tile<false>(Ks, Vs, qf0, qf1, l16, quad, i_tloc, l_run, o_acc);
        else if (n == diag_n)
            flash_tile<true>(Ks, Vs, qf0, qf1, l16, quad, i_tloc, l_run, o_acc);
        // waves with n > diag_n skip compute but still hit the barrier
    }

    // reduce l across the 4 quads sharing each query (once, not per tile)
    l_run += __shfl_xor(l_run, 16, 64);
    l_run += __shfl_xor(l_run, 32, 64);
    const float inv_l = 1.f / l_run;

    // epilogue: O^T -> O via padded LDS (stride 72), coalesced bf16 stores
    __syncthreads();                             // all waves done reading ring
    u16* Os = (u16*)smem;                        // 8 waves * 16 * 72 u16 = 18KB
#pragma unroll
    for (int td = 0; td < 4; td++) {
        u16x4 o;
#pragma unroll
        for (int r = 0; r < 4; r++) o[r] = f2bf(o_acc[td][r] * inv_l);
        *(u16x4*)&Os[wave * 1152 + l16 * 72 + td * 16 + quad * 4] = o;
    }
    __syncthreads();
    const int oi = lane >> 2, od = (lane & 3) * 16;
    u16x8 r0 = *(const u16x8*)&Os[wave * 1152 + oi * 72 + od];
    u16x8 r1 = *(const u16x8*)&Os[wave * 1152 + oi * 72 + od + 8];
    const size_t orow = ((size_t)b * Tq + q0w + (wave & 3) * 16 + oi) * Dq + h * 64 + od;
    *(u16x8*)&Ob[orow] = r0;
    *(u16x8*)&Ob[orow + 8] = r1;
}

// ---------------- launch ----------------
extern "C" void kernel_launch(void* const* d_in, const int* in_sizes, int n_in,
                              void* d_out, int out_size, void* d_ws, size_t ws_size,
                              hipStream_t stream) {
    const float* x     = (const float*)d_in[0];
    const float* cosT  = (const float*)d_in[1];
    const float* sinT  = (const float*)d_in[2];
    const float* Wqkv  = (const float*)d_in[3];
    const float* Wproj = (const float*)d_in[4];

    u16* xb     = (u16*)d_ws;                          // 8192*1024
    u16* wqkvb  = xb + (size_t)8192 * 1024;            // 3072*1024
    u16* wprojb = wqkvb + (size_t)3072 * 1024;         // 1024*1024
    u16* Qb     = wprojb + (size_t)1024 * 1024;        // 64*2048*64
    u16* Kb     = Qb + (size_t)64 * 2048 * 64;         // 64*2048*64
    f16* Vtg    = (f16*)(Kb + (size_t)64 * 2048 * 64); // 64*64*2048 (transposed)
    u16* attn   = (u16*)(Vtg + (size_t)64 * 64 * 2048);// 8192*1024

    cvt3_f32_bf16<<<12288, 256, 0, stream>>>(x, xb, 2097152,
                                             Wqkv, wqkvb, 786432,
                                             Wproj, wprojb, 262144);

    gemm_qkv<<<dim3(64, 24), 256, 0, stream>>>(xb, wqkvb, cosT, sinT, Qb, Kb, Vtg);
    flash<<<1024, 512, 0, stream>>>(Qb, Kb, Vtg, attn);
    gemm_bt<<<dim3(64, 8), 256, 0, stream>>>(attn, wprojb, (float*)d_out, 8192, 1024, 1024);
}